// Round 2
// baseline (301.890 us; speedup 1.0000x reference)
//
#include <hip/hip_runtime.h>
#include <hip/hip_bf16.h>

// GQA forward, MI355X. cast/transpose -> fused QKV GEMM (128^2 m97-structure)
// -> V^T transpose -> barrier-free all-register flash attention -> out GEMM.

typedef __attribute__((ext_vector_type(8))) short          bf16x8;
typedef __attribute__((ext_vector_type(4))) float          f32x4;
typedef __attribute__((ext_vector_type(4))) unsigned short u16x4;

#define DEV __device__ __forceinline__

static constexpr int BB   = 2;
static constexpr int SS   = 2048;
static constexpr int EMB  = 1024;
static constexpr int QKVD = 1536;   // Q(1024) | K(256) | V(256) fused output

DEV unsigned short f2b(float f) {
  union { float f; unsigned u; } v; v.f = f;
  unsigned r = (v.u + 0x7FFFu + ((v.u >> 16) & 1u)) >> 16;  // RNE
  return (unsigned short)r;
}

DEV unsigned packbf2(float a, float b) {
  __hip_bfloat162 h = __float22bfloat162_rn(make_float2(a, b));
  union { __hip_bfloat162 h; unsigned u; } c; c.h = h; return c.u;
}

DEV void gl_lds16(const void* g, void* l) {
  __builtin_amdgcn_global_load_lds((__attribute__((address_space(1))) void*)g,
                                   (__attribute__((address_space(3))) void*)l,
                                   16, 0, 0);
}

// ---------------- cast fp32 -> bf16 ---------------------------------------
__global__ __launch_bounds__(256) void cast_x_kernel(const float* __restrict__ x,
                                                     unsigned short* __restrict__ xb) {
  size_t i = ((size_t)blockIdx.x * 256 + threadIdx.x) * 4;
  f32x4 f = *(const f32x4*)(x + i);
  u16x4 o;
  o[0] = f2b(f[0]); o[1] = f2b(f[1]); o[2] = f2b(f[2]); o[3] = f2b(f[3]);
  *(u16x4*)(xb + i) = o;
}

// ---------------- transpose + cast: W[K=1024][N] fp32 -> Wt[N][1024] bf16 --
__global__ __launch_bounds__(256) void transpose_cast_kernel(const float* __restrict__ W,
                                                             unsigned short* __restrict__ Wt,
                                                             int N) {
  __shared__ unsigned short tile[64][72];
  const int kb = blockIdx.x * 64, nb = blockIdx.y * 64;
  const int tid = threadIdx.x;
#pragma unroll
  for (int p = 0; p < 16; ++p) {
    int i = tid + 256 * p;
    int k = i >> 6, n = i & 63;
    tile[k][n] = f2b(W[(size_t)(kb + k) * N + nb + n]);
  }
  __syncthreads();
#pragma unroll
  for (int p = 0; p < 16; ++p) {
    int i = tid + 256 * p;
    int n = i >> 6, k = i & 63;
    Wt[(size_t)(nb + n) * 1024 + kb + k] = tile[k][n];
  }
}

// ---------------- V^T: QKV cols [1280..1536) -> Vt[bg=b*4+g][d=64][s=2048] --
__global__ __launch_bounds__(256) void transpose_v(const unsigned short* __restrict__ QKV,
                                                   unsigned short* __restrict__ Vt) {
  __shared__ unsigned short t[64][72];
  const int s0 = blockIdx.x * 64;
  const int bg = blockIdx.y;
  const int b = bg >> 2, g = bg & 3;
  const int tid = threadIdx.x;
#pragma unroll
  for (int p = 0; p < 2; ++p) {
    int i = tid + 256 * p;              // 0..511
    int si = i >> 3, d0 = (i & 7) * 8;
    bf16x8 v = *(const bf16x8*)(QKV + ((size_t)(b * SS + s0 + si)) * QKVD + 1280 + g * 64 + d0);
#pragma unroll
    for (int j = 0; j < 8; ++j) t[si][d0 + j] = (unsigned short)v[j];
  }
  __syncthreads();
#pragma unroll
  for (int p = 0; p < 2; ++p) {
    int i = tid + 256 * p;
    int d = i >> 3, sv = (i & 7) * 8;
    bf16x8 vv;
#pragma unroll
    for (int j = 0; j < 8; ++j) vv[j] = (short)t[sv + j][d];
    *(bf16x8*)(Vt + ((size_t)(bg * 64 + d)) * SS + s0 + sv) = vv;
  }
}

// ---------------- GEMM: C[M,Nc] = A[M,K] * Bt[Nc,K]^T, 128x128 tile --------
// 256 thr = 4 waves (2x2), each wave 64x64 (4x4 16x16x32 frags), BK=32.
template <bool BF16_OUT, bool BIAS>
__global__ __launch_bounds__(256) void gemm128(const unsigned short* __restrict__ A,
                                               const unsigned short* __restrict__ Bt,
                                               void* __restrict__ Cv,
                                               const float* __restrict__ bias,
                                               int Nc, int Kd) {
  const int tid = threadIdx.x;
  const int w = tid >> 6, lane = tid & 63;
  const int l15 = lane & 15, l4 = lane >> 4;
  const int wr = w >> 1, wc = w & 1;
  const size_t rb = (size_t)blockIdx.x * 128;
  const size_t cb = (size_t)blockIdx.y * 128;

  __shared__ alignas(16) unsigned short sA[128 * 32];
  __shared__ alignas(16) unsigned short sB[128 * 32];

  f32x4 acc[4][4] = {};

  const unsigned short* Ap = A + (rb + 32 * w + (lane >> 2)) * (size_t)Kd + (lane & 3) * 8;
  const unsigned short* Bp = Bt + (cb + 32 * w + (lane >> 2)) * (size_t)Kd + (lane & 3) * 8;

  for (int k0 = 0; k0 < Kd; k0 += 32) {
    __syncthreads();
    gl_lds16(Ap + k0,                   &sA[1024 * w]);
    gl_lds16(Ap + 16 * (size_t)Kd + k0, &sA[1024 * w + 512]);
    gl_lds16(Bp + k0,                   &sB[1024 * w]);
    gl_lds16(Bp + 16 * (size_t)Kd + k0, &sB[1024 * w + 512]);
    asm volatile("s_waitcnt vmcnt(0)" ::: "memory");
    __syncthreads();

    bf16x8 af[4], bfr[4];
#pragma unroll
    for (int m = 0; m < 4; ++m)
      af[m] = *(const bf16x8*)&sA[(wr * 64 + m * 16 + l15) * 32 + 8 * l4];
#pragma unroll
    for (int n = 0; n < 4; ++n)
      bfr[n] = *(const bf16x8*)&sB[(wc * 64 + n * 16 + l15) * 32 + 8 * l4];
#pragma unroll
    for (int m = 0; m < 4; ++m)
#pragma unroll
      for (int n = 0; n < 4; ++n)
        acc[m][n] = __builtin_amdgcn_mfma_f32_16x16x32_bf16(af[m], bfr[n], acc[m][n], 0, 0, 0);
  }

#pragma unroll
  for (int m = 0; m < 4; ++m)
#pragma unroll
    for (int n = 0; n < 4; ++n) {
      float bv = 0.f;
      if constexpr (BIAS) bv = bias[cb + wc * 64 + n * 16 + l15];
#pragma unroll
      for (int r = 0; r < 4; ++r) {
        size_t row = rb + wr * 64 + m * 16 + 4 * l4 + r;
        size_t col = cb + wc * 64 + n * 16 + l15;
        if constexpr (BF16_OUT)
          ((unsigned short*)Cv)[row * Nc + col] = f2b(acc[m][n][r]);
        else
          ((float*)Cv)[row * Nc + col] = acc[m][n][r] + bv;
      }
    }
}

// ---------------- barrier-free flash attention -----------------------------
// 1 wave/block, grid (S/16, B*H). Wave owns 16 q rows; KV tile = 64.
// Swapped QK^T: S^T=mfma(K,Q) -> lane holds S[q=l15][kv=16c+4*l4+r].
// P relayout to PV A-frag via 16 shuffles. V^T frags straight from global.
__global__ __launch_bounds__(64) void attn_kernel(const unsigned short* __restrict__ QKV,
                                                  const unsigned short* __restrict__ Vt,
                                                  unsigned short* __restrict__ Ctx) {
  const int qt = blockIdx.x;            // 16-row q tile
  const int bh = blockIdx.y;
  const int b = bh >> 4, h = bh & 15, g = h >> 2;
  const int lane = threadIdx.x;
  const int l15 = lane & 15, l4 = lane >> 4;

  const int q_glob = qt * 16 + l15;

  const unsigned short* qp =
      QKV + ((size_t)(b * SS + qt * 16 + l15)) * QKVD + h * 64 + 8 * l4;
  bf16x8 qf0 = *(const bf16x8*)(qp);
  bf16x8 qf1 = *(const bf16x8*)(qp + 32);

  f32x4 o[4] = {};                      // O[q=4*l4+r][d=t*16+l15]
  float m_r = -1e30f, l_r = 0.f;

  const unsigned short* kbase =
      QKV + ((size_t)(b * SS)) * QKVD + 1024 + g * 64 + 8 * l4;
  const size_t vrow = (size_t)(((b << 2) | g) * 64);

  const int s0 = l15 | (((2 * l4) & 3) << 4);
  const int s1 = l15 | (((2 * l4 + 1) & 3) << 4);
  const bool hi = (l4 >= 2);

  const int nkv = (qt >> 2) + 1;
  for (int kt = 0; kt < nkv; ++kt) {
    const int kv0 = kt * 64;

    // S^T = (K Q^T): per c-tile, lane gets S[q=l15][kv0+16c+4*l4+r]
    f32x4 p[4];
#pragma unroll
    for (int c = 0; c < 4; ++c) {
      const unsigned short* kp = kbase + (size_t)(kv0 + c * 16 + l15) * QKVD;
      bf16x8 kf0 = *(const bf16x8*)kp;
      bf16x8 kf1 = *(const bf16x8*)(kp + 32);
      f32x4 z = {0.f, 0.f, 0.f, 0.f};
      z = __builtin_amdgcn_mfma_f32_16x16x32_bf16(kf0, qf0, z, 0, 0, 0);
      z = __builtin_amdgcn_mfma_f32_16x16x32_bf16(kf1, qf1, z, 0, 0, 0);
      p[c] = z;
    }

    // scale + causal mask + in-lane max
    float mx = -1e30f;
#pragma unroll
    for (int c = 0; c < 4; ++c)
#pragma unroll
      for (int r = 0; r < 4; ++r) {
        int kv = kv0 + c * 16 + 4 * l4 + r;
        float v = p[c][r] * 0.125f;
        v = (kv > q_glob) ? -1e30f : v;
        p[c][r] = v;
        mx = fmaxf(mx, v);
      }
    mx = fmaxf(mx, __shfl_xor(mx, 16));
    mx = fmaxf(mx, __shfl_xor(mx, 32));

    float mn = fmaxf(m_r, mx);
    float corr = __expf(m_r - mn);
    m_r = mn;

    // P = exp(S - m), bf16-pack, row sum
    float rs = 0.f;
    unsigned w0[4], w1[4];
#pragma unroll
    for (int c = 0; c < 4; ++c) {
      float e0 = __expf(p[c][0] - mn), e1 = __expf(p[c][1] - mn);
      float e2 = __expf(p[c][2] - mn), e3 = __expf(p[c][3] - mn);
      rs += (e0 + e1) + (e2 + e3);
      w0[c] = packbf2(e0, e1);
      w1[c] = packbf2(e2, e3);
    }
    rs += __shfl_xor(rs, 16);
    rs += __shfl_xor(rs, 32);
    l_r = l_r * corr + rs;

    // rescale O (corr is per q=l15; O rows are q=4*l4+r)
    f32x4 cf;
#pragma unroll
    for (int r = 0; r < 4; ++r) cf[r] = __shfl(corr, 4 * l4 + r);
#pragma unroll
    for (int t = 0; t < 4; ++t)
#pragma unroll
      for (int r = 0; r < 4; ++r) o[t][r] *= cf[r];

    // P relayout (dest lane (l15,l4),ks gets P[q=l15][32ks+8*l4+j]) + PV
#pragma unroll
    for (int ks = 0; ks < 2; ++ks) {
      unsigned a00 = __shfl(w0[2 * ks], s0), a01 = __shfl(w0[2 * ks + 1], s0);
      unsigned a10 = __shfl(w1[2 * ks], s0), a11 = __shfl(w1[2 * ks + 1], s0);
      unsigned b00 = __shfl(w0[2 * ks], s1), b01 = __shfl(w0[2 * ks + 1], s1);
      unsigned b10 = __shfl(w1[2 * ks], s1), b11 = __shfl(w1[2 * ks + 1], s1);
      union { bf16x8 v; unsigned u[4]; } pf;
      pf.u[0] = hi ? a01 : a00;
      pf.u[1] = hi ? a11 : a10;
      pf.u[2] = hi ? b01 : b00;
      pf.u[3] = hi ? b11 : b10;
#pragma unroll
      for (int t = 0; t < 4; ++t) {
        const unsigned short* vp =
            Vt + (vrow + t * 16 + l15) * (size_t)SS + kv0 + 32 * ks + 8 * l4;
        bf16x8 vf = *(const bf16x8*)vp;
        o[t] = __builtin_amdgcn_mfma_f32_16x16x32_bf16(pf.v, vf, o[t], 0, 0, 0);
      }
    }
  }

  f32x4 lf;
#pragma unroll
  for (int r = 0; r < 4; ++r) lf[r] = __shfl(l_r, 4 * l4 + r);
#pragma unroll
  for (int t = 0; t < 4; ++t)
#pragma unroll
    for (int r = 0; r < 4; ++r) {
      Ctx[((size_t)(b * SS + qt * 16 + 4 * l4 + r)) * 1024 + h * 64 + t * 16 + l15] =
          f2b(o[t][r] / lf[r]);
    }
}

// ---------------------------------------------------------------------------
extern "C" void kernel_launch(void* const* d_in, const int* in_sizes, int n_in,
                              void* d_out, int out_size, void* d_ws, size_t ws_size,
                              hipStream_t stream) {
  (void)in_sizes; (void)n_in; (void)out_size; (void)ws_size;
  const float* x  = (const float*)d_in[0];
  const float* Wq = (const float*)d_in[1];
  const float* Wk = (const float*)d_in[2];
  const float* Wv = (const float*)d_in[3];
  const float* Wo = (const float*)d_in[4];
  const float* bo = (const float*)d_in[5];
  float* out = (float*)d_out;

  char* ws = (char*)d_ws;
  unsigned short* x_bf   = (unsigned short*)(ws);                        // 8 MiB (aliased w/ Ctx)
  unsigned short* Ctx    = (unsigned short*)(ws);                        // 8 MiB
  unsigned short* QKVb   = (unsigned short*)(ws + (size_t)( 8u << 20));  // 12 MiB
  unsigned short* Wqkv_t = (unsigned short*)(ws + (size_t)(20u << 20));  // 3 MiB
  unsigned short* Wo_t   = (unsigned short*)(ws + (size_t)(23u << 20));  // 2 MiB
  unsigned short* Vtb    = (unsigned short*)(ws + (size_t)(25u << 20));  // 2 MiB

  const int M = BB * SS;  // 4096

  cast_x_kernel<<<dim3((M * EMB) / (256 * 4)), 256, 0, stream>>>(x, x_bf);
  transpose_cast_kernel<<<dim3(16, 16), 256, 0, stream>>>(Wq, Wqkv_t, 1024);
  transpose_cast_kernel<<<dim3(16, 4),  256, 0, stream>>>(Wk, Wqkv_t + (size_t)1024 * 1024, 256);
  transpose_cast_kernel<<<dim3(16, 4),  256, 0, stream>>>(Wv, Wqkv_t + (size_t)1280 * 1024, 256);
  transpose_cast_kernel<<<dim3(16, 16), 256, 0, stream>>>(Wo, Wo_t, 1024);

  gemm128<true, false><<<dim3(M / 128, QKVD / 128), 256, 0, stream>>>(
      x_bf, Wqkv_t, QKVb, nullptr, QKVD, EMB);

  transpose_v<<<dim3(SS / 64, 8), 256, 0, stream>>>(QKVb, Vtb);

  attn_kernel<<<dim3(SS / 16, BB * 16), 64, 0, stream>>>(QKVb, Vtb, Ctx);

  gemm128<false, true><<<dim3(M / 128, EMB / 128), 256, 0, stream>>>(
      Ctx, Wo_t, out, bo, EMB, EMB);
}

// Round 3
// 168.051 us; speedup vs baseline: 1.7964x; 1.7964x over previous
//
#include <hip/hip_runtime.h>
#include <hip/hip_bf16.h>

// GQA forward, MI355X. cast/transpose -> fused QKV GEMM (128^2 m97-structure)
// -> V^T transpose -> flash attention with LDS-staged K/V (global_load_lds,
// double-buffered, XOR-swizzled) + in-register softmax -> out GEMM.

typedef __attribute__((ext_vector_type(8))) short          bf16x8;
typedef __attribute__((ext_vector_type(4))) float          f32x4;
typedef __attribute__((ext_vector_type(4))) unsigned short u16x4;

#define DEV __device__ __forceinline__

static constexpr int BB   = 2;
static constexpr int SS   = 2048;
static constexpr int EMB  = 1024;
static constexpr int QKVD = 1536;   // Q(1024) | K(256) | V(256) fused output

DEV unsigned short f2b(float f) {
  union { float f; unsigned u; } v; v.f = f;
  unsigned r = (v.u + 0x7FFFu + ((v.u >> 16) & 1u)) >> 16;  // RNE
  return (unsigned short)r;
}

DEV unsigned packbf2(float a, float b) {
  __hip_bfloat162 h = __float22bfloat162_rn(make_float2(a, b));
  union { __hip_bfloat162 h; unsigned u; } c; c.h = h; return c.u;
}

DEV void gl_lds16(const void* g, void* l) {
  __builtin_amdgcn_global_load_lds((__attribute__((address_space(1))) void*)g,
                                   (__attribute__((address_space(3))) void*)l,
                                   16, 0, 0);
}

// ---------------- cast fp32 -> bf16 ---------------------------------------
__global__ __launch_bounds__(256) void cast_x_kernel(const float* __restrict__ x,
                                                     unsigned short* __restrict__ xb) {
  size_t i = ((size_t)blockIdx.x * 256 + threadIdx.x) * 4;
  f32x4 f = *(const f32x4*)(x + i);
  u16x4 o;
  o[0] = f2b(f[0]); o[1] = f2b(f[1]); o[2] = f2b(f[2]); o[3] = f2b(f[3]);
  *(u16x4*)(xb + i) = o;
}

// ---------------- transpose + cast: W[K=1024][N] fp32 -> Wt[N][1024] bf16 --
__global__ __launch_bounds__(256) void transpose_cast_kernel(const float* __restrict__ W,
                                                             unsigned short* __restrict__ Wt,
                                                             int N) {
  __shared__ unsigned short tile[64][72];
  const int kb = blockIdx.x * 64, nb = blockIdx.y * 64;
  const int tid = threadIdx.x;
#pragma unroll
  for (int p = 0; p < 16; ++p) {
    int i = tid + 256 * p;
    int k = i >> 6, n = i & 63;
    tile[k][n] = f2b(W[(size_t)(kb + k) * N + nb + n]);
  }
  __syncthreads();
#pragma unroll
  for (int p = 0; p < 16; ++p) {
    int i = tid + 256 * p;
    int n = i >> 6, k = i & 63;
    Wt[(size_t)(nb + n) * 1024 + kb + k] = tile[k][n];
  }
}

// ---------------- V^T: QKV cols [1280..1536) -> Vt[bg=b*4+g][d=64][s=2048] --
__global__ __launch_bounds__(256) void transpose_v(const unsigned short* __restrict__ QKV,
                                                   unsigned short* __restrict__ Vt) {
  __shared__ unsigned short t[64][72];
  const int s0 = blockIdx.x * 64;
  const int bg = blockIdx.y;
  const int b = bg >> 2, g = bg & 3;
  const int tid = threadIdx.x;
#pragma unroll
  for (int p = 0; p < 2; ++p) {
    int i = tid + 256 * p;              // 0..511
    int si = i >> 3, d0 = (i & 7) * 8;
    bf16x8 v = *(const bf16x8*)(QKV + ((size_t)(b * SS + s0 + si)) * QKVD + 1280 + g * 64 + d0);
#pragma unroll
    for (int j = 0; j < 8; ++j) t[si][d0 + j] = (unsigned short)v[j];
  }
  __syncthreads();
#pragma unroll
  for (int p = 0; p < 2; ++p) {
    int i = tid + 256 * p;
    int d = i >> 3, sv = (i & 7) * 8;
    bf16x8 vv;
#pragma unroll
    for (int j = 0; j < 8; ++j) vv[j] = (short)t[sv + j][d];
    *(bf16x8*)(Vt + ((size_t)(bg * 64 + d)) * SS + s0 + sv) = vv;
  }
}

// ---------------- GEMM: C[M,Nc] = A[M,K] * Bt[Nc,K]^T, 128x128 tile --------
template <bool BF16_OUT, bool BIAS>
__global__ __launch_bounds__(256) void gemm128(const unsigned short* __restrict__ A,
                                               const unsigned short* __restrict__ Bt,
                                               void* __restrict__ Cv,
                                               const float* __restrict__ bias,
                                               int Nc, int Kd) {
  const int tid = threadIdx.x;
  const int w = tid >> 6, lane = tid & 63;
  const int l15 = lane & 15, l4 = lane >> 4;
  const int wr = w >> 1, wc = w & 1;
  const size_t rb = (size_t)blockIdx.x * 128;
  const size_t cb = (size_t)blockIdx.y * 128;

  __shared__ alignas(16) unsigned short sA[128 * 32];
  __shared__ alignas(16) unsigned short sB[128 * 32];

  f32x4 acc[4][4] = {};

  const unsigned short* Ap = A + (rb + 32 * w + (lane >> 2)) * (size_t)Kd + (lane & 3) * 8;
  const unsigned short* Bp = Bt + (cb + 32 * w + (lane >> 2)) * (size_t)Kd + (lane & 3) * 8;

  for (int k0 = 0; k0 < Kd; k0 += 32) {
    __syncthreads();
    gl_lds16(Ap + k0,                   &sA[1024 * w]);
    gl_lds16(Ap + 16 * (size_t)Kd + k0, &sA[1024 * w + 512]);
    gl_lds16(Bp + k0,                   &sB[1024 * w]);
    gl_lds16(Bp + 16 * (size_t)Kd + k0, &sB[1024 * w + 512]);
    asm volatile("s_waitcnt vmcnt(0)" ::: "memory");
    __syncthreads();

    bf16x8 af[4], bfr[4];
#pragma unroll
    for (int m = 0; m < 4; ++m)
      af[m] = *(const bf16x8*)&sA[(wr * 64 + m * 16 + l15) * 32 + 8 * l4];
#pragma unroll
    for (int n = 0; n < 4; ++n)
      bfr[n] = *(const bf16x8*)&sB[(wc * 64 + n * 16 + l15) * 32 + 8 * l4];
#pragma unroll
    for (int m = 0; m < 4; ++m)
#pragma unroll
      for (int n = 0; n < 4; ++n)
        acc[m][n] = __builtin_amdgcn_mfma_f32_16x16x32_bf16(af[m], bfr[n], acc[m][n], 0, 0, 0);
  }

#pragma unroll
  for (int m = 0; m < 4; ++m)
#pragma unroll
    for (int n = 0; n < 4; ++n) {
      float bv = 0.f;
      if constexpr (BIAS) bv = bias[cb + wc * 64 + n * 16 + l15];
#pragma unroll
      for (int r = 0; r < 4; ++r) {
        size_t row = rb + wr * 64 + m * 16 + 4 * l4 + r;
        size_t col = cb + wc * 64 + n * 16 + l15;
        if constexpr (BF16_OUT)
          ((unsigned short*)Cv)[row * Nc + col] = f2b(acc[m][n][r]);
        else
          ((float*)Cv)[row * Nc + col] = acc[m][n][r] + bv;
      }
    }
}

// ---------------- flash attention, LDS-staged K/V --------------------------
// Block = (64 q-rows, b, h): 4 waves x 16 q-rows. K tile [64kv][64d] and
// V^T tile [64d][64kv] staged via global_load_lds (16B/lane, contiguous),
// double-buffered, XOR-swizzled (chunk ^= row&7; pre-swizzled global source,
// swizzled ds_read). Softmax fully in-register (swapped QK^T).
__global__ __launch_bounds__(256) void attn_kernel(const unsigned short* __restrict__ QKV,
                                                   const unsigned short* __restrict__ Vt,
                                                   unsigned short* __restrict__ Ctx) {
  const int qt = 31 - blockIdx.x;        // reversed: long blocks dispatch first
  const int bh = blockIdx.y;
  const int b = bh >> 4, h = bh & 15, g = h >> 2;
  const int tid = threadIdx.x;
  const int w = tid >> 6, lane = tid & 63;
  const int l15 = lane & 15, l4 = lane >> 4;

  __shared__ alignas(16) unsigned short sK[2][64 * 64];
  __shared__ alignas(16) unsigned short sV[2][64 * 64];

  const int qb = qt * 64;
  const int q_glob = qb + w * 16 + l15;

  const unsigned short* qp =
      QKV + ((size_t)(b * SS + qb + w * 16 + l15)) * QKVD + h * 64 + 8 * l4;
  bf16x8 qf0 = *(const bf16x8*)(qp);
  bf16x8 qf1 = *(const bf16x8*)(qp + 32);

  f32x4 o[4] = {};                      // O[q=4*l4+r][d=t*16+l15]
  float m_r = -1e30f, l_r = 0.f;

  // staging geometry: chunk id cid in [0,512), row=cid>>3, c=cid&7,
  // global chunk cg = c ^ (row&7)  (so LDS[row][c] = G[row][c^(row&7)])
  const int srow = tid >> 3;            // rows 0..31 (pass 0), +32 (pass 1)
  const int sc   = tid & 7;
  const unsigned short* kstage0 =
      QKV + ((size_t)(b * SS + srow)) * QKVD + 1024 + g * 64 + (sc ^ (srow & 7)) * 8;
  const unsigned short* kstage1 =
      QKV + ((size_t)(b * SS + srow + 32)) * QKVD + 1024 + g * 64 + (sc ^ ((srow + 32) & 7)) * 8;
  const unsigned short* vstage0 =
      Vt + ((size_t)(((b << 2) | g) * 64 + srow)) * SS + (sc ^ (srow & 7)) * 8;
  const unsigned short* vstage1 =
      Vt + ((size_t)(((b << 2) | g) * 64 + srow + 32)) * SS + (sc ^ ((srow + 32) & 7)) * 8;

  const int xsw = (l15 & 7);            // read-side swizzle key

  const int s0 = l15 | (((2 * l4) & 3) << 4);
  const int s1 = l15 | (((2 * l4 + 1) & 3) << 4);
  const bool hi = (l4 >= 2);

  const int nkv = qt + 1;

  // prologue: stage tile 0
  {
    char* kb0 = (char*)&sK[0][0] + (w << 10);
    char* vb0 = (char*)&sV[0][0] + (w << 10);
    gl_lds16(kstage0, kb0);
    gl_lds16(kstage1, kb0 + 4096);
    gl_lds16(vstage0, vb0);
    gl_lds16(vstage1, vb0 + 4096);
  }
  asm volatile("s_waitcnt vmcnt(0)" ::: "memory");
  __syncthreads();

  for (int kt = 0; kt < nkv; ++kt) {
    const int kv0 = kt * 64;
    const int cur = kt & 1;

    // issue next tile's staging loads (hidden under compute)
    if (kt + 1 < nkv) {
      const size_t koff = (size_t)(kv0 + 64) * QKVD;
      const size_t voff = (size_t)(kv0 + 64);
      char* kb = (char*)&sK[cur ^ 1][0] + (w << 10);
      char* vb = (char*)&sV[cur ^ 1][0] + (w << 10);
      gl_lds16(kstage0 + koff, kb);
      gl_lds16(kstage1 + koff, kb + 4096);
      gl_lds16(vstage0 + voff, vb);
      gl_lds16(vstage1 + voff, vb + 4096);
    }

    // S^T = (K Q^T): lane gets S[q=l15][kv0+16c+4*l4+r]
    f32x4 p[4];
#pragma unroll
    for (int c = 0; c < 4; ++c) {
      const unsigned short* krow = &sK[cur][(c * 16 + l15) * 64];
      bf16x8 kf0 = *(const bf16x8*)&krow[((l4 ^ xsw)) * 8];
      bf16x8 kf1 = *(const bf16x8*)&krow[(((4 | l4) ^ xsw)) * 8];
      f32x4 z = {0.f, 0.f, 0.f, 0.f};
      z = __builtin_amdgcn_mfma_f32_16x16x32_bf16(kf0, qf0, z, 0, 0, 0);
      z = __builtin_amdgcn_mfma_f32_16x16x32_bf16(kf1, qf1, z, 0, 0, 0);
      p[c] = z;
    }

    // scale + causal mask + in-lane max
    float mx = -1e30f;
#pragma unroll
    for (int c = 0; c < 4; ++c)
#pragma unroll
      for (int r = 0; r < 4; ++r) {
        int kv = kv0 + c * 16 + 4 * l4 + r;
        float v = p[c][r] * 0.125f;
        v = (kv > q_glob) ? -1e30f : v;
        p[c][r] = v;
        mx = fmaxf(mx, v);
      }
    mx = fmaxf(mx, __shfl_xor(mx, 16));
    mx = fmaxf(mx, __shfl_xor(mx, 32));

    float mn = fmaxf(m_r, mx);
    float corr = __expf(m_r - mn);
    m_r = mn;

    // P = exp(S - m), bf16-pack, row sum
    float rs = 0.f;
    unsigned w0[4], w1[4];
#pragma unroll
    for (int c = 0; c < 4; ++c) {
      float e0 = __expf(p[c][0] - mn), e1 = __expf(p[c][1] - mn);
      float e2 = __expf(p[c][2] - mn), e3 = __expf(p[c][3] - mn);
      rs += (e0 + e1) + (e2 + e3);
      w0[c] = packbf2(e0, e1);
      w1[c] = packbf2(e2, e3);
    }
    rs += __shfl_xor(rs, 16);
    rs += __shfl_xor(rs, 32);
    l_r = l_r * corr + rs;

    // rescale O
    f32x4 cf;
#pragma unroll
    for (int r = 0; r < 4; ++r) cf[r] = __shfl(corr, 4 * l4 + r);
#pragma unroll
    for (int t = 0; t < 4; ++t)
#pragma unroll
      for (int r = 0; r < 4; ++r) o[t][r] *= cf[r];

    // P relayout + PV (V^T from swizzled LDS)
#pragma unroll
    for (int ks = 0; ks < 2; ++ks) {
      unsigned a00 = __shfl(w0[2 * ks], s0), a01 = __shfl(w0[2 * ks + 1], s0);
      unsigned a10 = __shfl(w1[2 * ks], s0), a11 = __shfl(w1[2 * ks + 1], s0);
      unsigned b00 = __shfl(w0[2 * ks], s1), b01 = __shfl(w0[2 * ks + 1], s1);
      unsigned b10 = __shfl(w1[2 * ks], s1), b11 = __shfl(w1[2 * ks + 1], s1);
      union { bf16x8 v; unsigned u[4]; } pf;
      pf.u[0] = hi ? a01 : a00;
      pf.u[1] = hi ? a11 : a10;
      pf.u[2] = hi ? b01 : b00;
      pf.u[3] = hi ? b11 : b10;
#pragma unroll
      for (int t = 0; t < 4; ++t) {
        const unsigned short* vrow = &sV[cur][(t * 16 + l15) * 64];
        bf16x8 vf = *(const bf16x8*)&vrow[(((4 * ks + l4) ^ xsw)) * 8];
        o[t] = __builtin_amdgcn_mfma_f32_16x16x32_bf16(pf.v, vf, o[t], 0, 0, 0);
      }
    }

    asm volatile("s_waitcnt vmcnt(0)" ::: "memory");
    __syncthreads();
  }

  f32x4 lf;
#pragma unroll
  for (int r = 0; r < 4; ++r) lf[r] = __shfl(l_r, 4 * l4 + r);
#pragma unroll
  for (int t = 0; t < 4; ++t)
#pragma unroll
    for (int r = 0; r < 4; ++r) {
      Ctx[((size_t)(b * SS + qb + w * 16 + 4 * l4 + r)) * 1024 + h * 64 + t * 16 + l15] =
          f2b(o[t][r] / lf[r]);
    }
}

// ---------------------------------------------------------------------------
extern "C" void kernel_launch(void* const* d_in, const int* in_sizes, int n_in,
                              void* d_out, int out_size, void* d_ws, size_t ws_size,
                              hipStream_t stream) {
  (void)in_sizes; (void)n_in; (void)out_size; (void)ws_size;
  const float* x  = (const float*)d_in[0];
  const float* Wq = (const float*)d_in[1];
  const float* Wk = (const float*)d_in[2];
  const float* Wv = (const float*)d_in[3];
  const float* Wo = (const float*)d_in[4];
  const float* bo = (const float*)d_in[5];
  float* out = (float*)d_out;

  char* ws = (char*)d_ws;
  unsigned short* x_bf   = (unsigned short*)(ws);                        // 8 MiB (aliased w/ Ctx)
  unsigned short* Ctx    = (unsigned short*)(ws);                        // 8 MiB
  unsigned short* QKVb   = (unsigned short*)(ws + (size_t)( 8u << 20));  // 12 MiB
  unsigned short* Wqkv_t = (unsigned short*)(ws + (size_t)(20u << 20));  // 3 MiB
  unsigned short* Wo_t   = (unsigned short*)(ws + (size_t)(23u << 20));  // 2 MiB
  unsigned short* Vtb    = (unsigned short*)(ws + (size_t)(25u << 20));  // 2 MiB

  const int M = BB * SS;  // 4096

  cast_x_kernel<<<dim3((M * EMB) / (256 * 4)), 256, 0, stream>>>(x, x_bf);
  transpose_cast_kernel<<<dim3(16, 16), 256, 0, stream>>>(Wq, Wqkv_t, 1024);
  transpose_cast_kernel<<<dim3(16, 4),  256, 0, stream>>>(Wk, Wqkv_t + (size_t)1024 * 1024, 256);
  transpose_cast_kernel<<<dim3(16, 4),  256, 0, stream>>>(Wv, Wqkv_t + (size_t)1280 * 1024, 256);
  transpose_cast_kernel<<<dim3(16, 16), 256, 0, stream>>>(Wo, Wo_t, 1024);

  gemm128<true, false><<<dim3(M / 128, QKVD / 128), 256, 0, stream>>>(
      x_bf, Wqkv_t, QKVb, nullptr, QKVD, EMB);

  transpose_v<<<dim3(SS / 64, 8), 256, 0, stream>>>(QKVb, Vtb);

  attn_kernel<<<dim3(32, BB * 16), 256, 0, stream>>>(QKVb, Vtb, Ctx);

  gemm128<false, true><<<dim3(M / 128, EMB / 128), 256, 0, stream>>>(
      Ctx, Wo_t, out, bo, EMB, EMB);
}

// Round 4
// 130.815 us; speedup vs baseline: 2.3078x; 1.2846x over previous
//
#include <hip/hip_runtime.h>
#include <hip/hip_bf16.h>

// GQA forward, MI355X. cast/transpose -> fused QKV GEMM (128^2) -> V^T
// transpose -> flash attention (paired complementary q-tiles per block,
// interleaved; LDS-staged K/V double-buffered + XOR-swizzled; exp2-domain
// softmax with defer-max) -> out GEMM + bias.

typedef __attribute__((ext_vector_type(8))) short          bf16x8;
typedef __attribute__((ext_vector_type(4))) float          f32x4;
typedef __attribute__((ext_vector_type(4))) unsigned short u16x4;

#define DEV __device__ __forceinline__

static constexpr int BB   = 2;
static constexpr int SS   = 2048;
static constexpr int EMB  = 1024;
static constexpr int QKVD = 1536;   // Q(1024) | K(256) | V(256) fused output
static constexpr float SC2 = 0.18033688011112042f;  // 0.125 * log2(e)

DEV unsigned short f2b(float f) {
  union { float f; unsigned u; } v; v.f = f;
  unsigned r = (v.u + 0x7FFFu + ((v.u >> 16) & 1u)) >> 16;  // RNE
  return (unsigned short)r;
}

DEV unsigned packbf2(float a, float b) {
  __hip_bfloat162 h = __float22bfloat162_rn(make_float2(a, b));
  union { __hip_bfloat162 h; unsigned u; } c; c.h = h; return c.u;
}

DEV void gl_lds16(const void* g, void* l) {
  __builtin_amdgcn_global_load_lds((__attribute__((address_space(1))) void*)g,
                                   (__attribute__((address_space(3))) void*)l,
                                   16, 0, 0);
}

// ---------------- cast fp32 -> bf16 ---------------------------------------
__global__ __launch_bounds__(256) void cast_x_kernel(const float* __restrict__ x,
                                                     unsigned short* __restrict__ xb) {
  size_t i = ((size_t)blockIdx.x * 256 + threadIdx.x) * 4;
  f32x4 f = *(const f32x4*)(x + i);
  u16x4 o;
  o[0] = f2b(f[0]); o[1] = f2b(f[1]); o[2] = f2b(f[2]); o[3] = f2b(f[3]);
  *(u16x4*)(xb + i) = o;
}

// ---------------- transpose + cast: W[K=1024][N] fp32 -> Wt[N][1024] bf16 --
__global__ __launch_bounds__(256) void transpose_cast_kernel(const float* __restrict__ W,
                                                             unsigned short* __restrict__ Wt,
                                                             int N) {
  __shared__ unsigned short tile[64][72];
  const int kb = blockIdx.x * 64, nb = blockIdx.y * 64;
  const int tid = threadIdx.x;
#pragma unroll
  for (int p = 0; p < 16; ++p) {
    int i = tid + 256 * p;
    int k = i >> 6, n = i & 63;
    tile[k][n] = f2b(W[(size_t)(kb + k) * N + nb + n]);
  }
  __syncthreads();
#pragma unroll
  for (int p = 0; p < 16; ++p) {
    int i = tid + 256 * p;
    int n = i >> 6, k = i & 63;
    Wt[(size_t)(nb + n) * 1024 + kb + k] = tile[k][n];
  }
}

// ---------------- V^T: QKV cols [1280..1536) -> Vt[bg=b*4+g][d=64][s=2048] --
__global__ __launch_bounds__(256) void transpose_v(const unsigned short* __restrict__ QKV,
                                                   unsigned short* __restrict__ Vt) {
  __shared__ unsigned short t[64][72];
  const int s0 = blockIdx.x * 64;
  const int bg = blockIdx.y;
  const int b = bg >> 2, g = bg & 3;
  const int tid = threadIdx.x;
#pragma unroll
  for (int p = 0; p < 2; ++p) {
    int i = tid + 256 * p;
    int si = i >> 3, d0 = (i & 7) * 8;
    bf16x8 v = *(const bf16x8*)(QKV + ((size_t)(b * SS + s0 + si)) * QKVD + 1280 + g * 64 + d0);
#pragma unroll
    for (int j = 0; j < 8; ++j) t[si][d0 + j] = (unsigned short)v[j];
  }
  __syncthreads();
#pragma unroll
  for (int p = 0; p < 2; ++p) {
    int i = tid + 256 * p;
    int d = i >> 3, sv = (i & 7) * 8;
    bf16x8 vv;
#pragma unroll
    for (int j = 0; j < 8; ++j) vv[j] = (short)t[sv + j][d];
    *(bf16x8*)(Vt + ((size_t)(bg * 64 + d)) * SS + s0 + sv) = vv;
  }
}

// ---------------- GEMM: C[M,Nc] = A[M,K] * Bt[Nc,K]^T, 128x128 tile --------
template <bool BF16_OUT, bool BIAS>
__global__ __launch_bounds__(256) void gemm128(const unsigned short* __restrict__ A,
                                               const unsigned short* __restrict__ Bt,
                                               void* __restrict__ Cv,
                                               const float* __restrict__ bias,
                                               int Nc, int Kd) {
  const int tid = threadIdx.x;
  const int w = tid >> 6, lane = tid & 63;
  const int l15 = lane & 15, l4 = lane >> 4;
  const int wr = w >> 1, wc = w & 1;
  const size_t rb = (size_t)blockIdx.x * 128;
  const size_t cb = (size_t)blockIdx.y * 128;

  __shared__ alignas(16) unsigned short sA[128 * 32];
  __shared__ alignas(16) unsigned short sB[128 * 32];

  f32x4 acc[4][4] = {};

  const unsigned short* Ap = A + (rb + 32 * w + (lane >> 2)) * (size_t)Kd + (lane & 3) * 8;
  const unsigned short* Bp = Bt + (cb + 32 * w + (lane >> 2)) * (size_t)Kd + (lane & 3) * 8;

  for (int k0 = 0; k0 < Kd; k0 += 32) {
    __syncthreads();
    gl_lds16(Ap + k0,                   &sA[1024 * w]);
    gl_lds16(Ap + 16 * (size_t)Kd + k0, &sA[1024 * w + 512]);
    gl_lds16(Bp + k0,                   &sB[1024 * w]);
    gl_lds16(Bp + 16 * (size_t)Kd + k0, &sB[1024 * w + 512]);
    asm volatile("s_waitcnt vmcnt(0)" ::: "memory");
    __syncthreads();

    bf16x8 af[4], bfr[4];
#pragma unroll
    for (int m = 0; m < 4; ++m)
      af[m] = *(const bf16x8*)&sA[(wr * 64 + m * 16 + l15) * 32 + 8 * l4];
#pragma unroll
    for (int n = 0; n < 4; ++n)
      bfr[n] = *(const bf16x8*)&sB[(wc * 64 + n * 16 + l15) * 32 + 8 * l4];
#pragma unroll
    for (int m = 0; m < 4; ++m)
#pragma unroll
      for (int n = 0; n < 4; ++n)
        acc[m][n] = __builtin_amdgcn_mfma_f32_16x16x32_bf16(af[m], bfr[n], acc[m][n], 0, 0, 0);
  }

#pragma unroll
  for (int m = 0; m < 4; ++m)
#pragma unroll
    for (int n = 0; n < 4; ++n) {
      float bv = 0.f;
      if constexpr (BIAS) bv = bias[cb + wc * 64 + n * 16 + l15];
#pragma unroll
      for (int r = 0; r < 4; ++r) {
        size_t row = rb + wr * 64 + m * 16 + 4 * l4 + r;
        size_t col = cb + wc * 64 + n * 16 + l15;
        if constexpr (BF16_OUT)
          ((unsigned short*)Cv)[row * Nc + col] = f2b(acc[m][n][r]);
        else
          ((float*)Cv)[row * Nc + col] = acc[m][n][r] + bv;
      }
    }
}

// ---------------- flash attention -----------------------------------------
struct QS {
  bf16x8 qf0, qf1;
  f32x4 o[4];
  float m2, l;
  int qg;
};

DEV void qs_init(QS& s, const unsigned short* __restrict__ QKV,
                 int b, int h, int qt, int w, int l15, int l4) {
  s.qg = qt * 64 + w * 16 + l15;
  const unsigned short* qp =
      QKV + ((size_t)(b * SS + qt * 64 + w * 16 + l15)) * QKVD + h * 64 + 8 * l4;
  s.qf0 = *(const bf16x8*)qp;
  s.qf1 = *(const bf16x8*)(qp + 32);
#pragma unroll
  for (int t = 0; t < 4; ++t) s.o[t] = f32x4{0.f, 0.f, 0.f, 0.f};
  s.m2 = -3e38f;
  s.l = 0.f;
}

// one K/V tile for one q-state; exp2-domain online softmax with defer-max
DEV void qs_tile(QS& st, const unsigned short* __restrict__ sKc,
                 const unsigned short* __restrict__ sVc,
                 int kv0, bool masked,
                 int l15, int l4, int xsw, int s0, int s1, bool hi) {
  // S^T = (K Q^T): lane gets S[q=l15][kv0+16c+4*l4+r]
  f32x4 p[4];
#pragma unroll
  for (int c = 0; c < 4; ++c) {
    const unsigned short* krow = &sKc[(c * 16 + l15) * 64];
    bf16x8 kf0 = *(const bf16x8*)&krow[(l4 ^ xsw) * 8];
    bf16x8 kf1 = *(const bf16x8*)&krow[((4 | l4) ^ xsw) * 8];
    f32x4 z = {0.f, 0.f, 0.f, 0.f};
    z = __builtin_amdgcn_mfma_f32_16x16x32_bf16(kf0, st.qf0, z, 0, 0, 0);
    z = __builtin_amdgcn_mfma_f32_16x16x32_bf16(kf1, st.qf1, z, 0, 0, 0);
    p[c] = z;
  }

  if (masked) {
#pragma unroll
    for (int c = 0; c < 4; ++c)
#pragma unroll
      for (int r = 0; r < 4; ++r) {
        int kv = kv0 + c * 16 + 4 * l4 + r;
        if (kv > st.qg) p[c][r] = -3e38f;
      }
  }

  float mx = -3e38f;
#pragma unroll
  for (int c = 0; c < 4; ++c)
#pragma unroll
    for (int r = 0; r < 4; ++r) mx = fmaxf(mx, p[c][r]);
  mx = fmaxf(mx, __shfl_xor(mx, 16));
  mx = fmaxf(mx, __shfl_xor(mx, 32));
  float mx2 = mx * SC2;

  // defer-max: skip rescale when growth bounded (P <= 2^8, bf16-safe)
  if (!__all(mx2 <= st.m2 + 8.f)) {
    float mn = fmaxf(st.m2, mx2);
    float corr = exp2f(st.m2 - mn);
    st.m2 = mn;
    st.l *= corr;
    f32x4 cf;
#pragma unroll
    for (int r = 0; r < 4; ++r) cf[r] = __shfl(corr, 4 * l4 + r);
#pragma unroll
    for (int t = 0; t < 4; ++t)
#pragma unroll
      for (int r = 0; r < 4; ++r) st.o[t][r] *= cf[r];
  }

  // P = exp2(S*SC2 - m2), bf16-pack, row sum
  float rs = 0.f;
  unsigned w0[4], w1[4];
#pragma unroll
  for (int c = 0; c < 4; ++c) {
    float e0 = exp2f(fmaf(p[c][0], SC2, -st.m2));
    float e1 = exp2f(fmaf(p[c][1], SC2, -st.m2));
    float e2 = exp2f(fmaf(p[c][2], SC2, -st.m2));
    float e3 = exp2f(fmaf(p[c][3], SC2, -st.m2));
    rs += (e0 + e1) + (e2 + e3);
    w0[c] = packbf2(e0, e1);
    w1[c] = packbf2(e2, e3);
  }
  rs += __shfl_xor(rs, 16);
  rs += __shfl_xor(rs, 32);
  st.l += rs;

  // P relayout (dest lane (l15,l4),ks gets P[q=l15][32ks+8*l4+j]) + PV
#pragma unroll
  for (int ks = 0; ks < 2; ++ks) {
    unsigned a00 = __shfl(w0[2 * ks], s0), a01 = __shfl(w0[2 * ks + 1], s0);
    unsigned a10 = __shfl(w1[2 * ks], s0), a11 = __shfl(w1[2 * ks + 1], s0);
    unsigned b00 = __shfl(w0[2 * ks], s1), b01 = __shfl(w0[2 * ks + 1], s1);
    unsigned b10 = __shfl(w1[2 * ks], s1), b11 = __shfl(w1[2 * ks + 1], s1);
    union { bf16x8 v; unsigned u[4]; } pf;
    pf.u[0] = hi ? a01 : a00;
    pf.u[1] = hi ? a11 : a10;
    pf.u[2] = hi ? b01 : b00;
    pf.u[3] = hi ? b11 : b10;
#pragma unroll
    for (int t = 0; t < 4; ++t) {
      const unsigned short* vrow = &sVc[(t * 16 + l15) * 64];
      bf16x8 vf = *(const bf16x8*)&vrow[((4 * ks + l4) ^ xsw) * 8];
      st.o[t] = __builtin_amdgcn_mfma_f32_16x16x32_bf16(pf.v, vf, st.o[t], 0, 0, 0);
    }
  }
}

DEV void qs_write(const QS& st, unsigned short* __restrict__ Ctx,
                  int b, int h, int qt, int w, int l15, int l4) {
  f32x4 lf;
#pragma unroll
  for (int r = 0; r < 4; ++r) lf[r] = __shfl(st.l, 4 * l4 + r);
#pragma unroll
  for (int t = 0; t < 4; ++t)
#pragma unroll
    for (int r = 0; r < 4; ++r) {
      Ctx[((size_t)(b * SS + qt * 64 + w * 16 + 4 * l4 + r)) * 1024 + h * 64 + t * 16 + l15] =
          f2b(st.o[t][r] / lf[r]);
    }
}

// Block f (512 total): xcd=f&7, bh=xcd*4+(t&3) (one (b,g) KV slice per XCD),
// complementary pair (qtA=31-pairi, qtB=pairi); f vs f+256 get p vs 15-p so
// per-CU round counts are uniform. B's tiles are a prefix of A's -> one
// staged K/V tile feeds both chains (ILP + fewer rounds).
__global__ __launch_bounds__(256) void attn_kernel(const unsigned short* __restrict__ QKV,
                                                   const unsigned short* __restrict__ Vt,
                                                   unsigned short* __restrict__ Ctx) {
  const int f = blockIdx.x;
  const int xcd = f & 7;
  const int t5 = (f >> 3) & 31;
  const int hi8 = f >> 8;
  const int bh = xcd * 4 + (t5 & 3);
  const int p8 = t5 >> 2;
  const int pairi = hi8 ? 15 - p8 : p8;
  const int qtA = 31 - pairi, qtB = pairi;
  const int nkvA = qtA + 1, nkvB = qtB + 1;

  const int b = bh >> 4, h = bh & 15, g = h >> 2;
  const int tid = threadIdx.x;
  const int w = tid >> 6, lane = tid & 63;
  const int l15 = lane & 15, l4 = lane >> 4;

  __shared__ alignas(16) unsigned short sK[2][64 * 64];
  __shared__ alignas(16) unsigned short sV[2][64 * 64];

  QS A, B;
  qs_init(A, QKV, b, h, qtA, w, l15, l4);
  qs_init(B, QKV, b, h, qtB, w, l15, l4);

  // staging geometry: LDS[row][c] = G[row][c ^ (row&7)] (16B chunks)
  const int srow = tid >> 3;
  const int sc   = tid & 7;
  const unsigned short* kstage0 =
      QKV + ((size_t)(b * SS + srow)) * QKVD + 1024 + g * 64 + (sc ^ (srow & 7)) * 8;
  const unsigned short* kstage1 =
      QKV + ((size_t)(b * SS + srow + 32)) * QKVD + 1024 + g * 64 + (sc ^ ((srow + 32) & 7)) * 8;
  const unsigned short* vstage0 =
      Vt + ((size_t)(((b << 2) | g) * 64 + srow)) * SS + (sc ^ (srow & 7)) * 8;
  const unsigned short* vstage1 =
      Vt + ((size_t)(((b << 2) | g) * 64 + srow + 32)) * SS + (sc ^ ((srow + 32) & 7)) * 8;

  const int xsw = (l15 & 7);
  const int s0 = l15 | (((2 * l4) & 3) << 4);
  const int s1 = l15 | (((2 * l4 + 1) & 3) << 4);
  const bool hi = (l4 >= 2);

  {
    char* kb0 = (char*)&sK[0][0] + (w << 10);
    char* vb0 = (char*)&sV[0][0] + (w << 10);
    gl_lds16(kstage0, kb0);
    gl_lds16(kstage1, kb0 + 4096);
    gl_lds16(vstage0, vb0);
    gl_lds16(vstage1, vb0 + 4096);
  }
  asm volatile("s_waitcnt vmcnt(0)" ::: "memory");
  __syncthreads();

  for (int kt = 0; kt < nkvA; ++kt) {
    const int kv0 = kt * 64;
    const int cur = kt & 1;

    if (kt + 1 < nkvA) {
      const size_t koff = (size_t)(kv0 + 64) * QKVD;
      const size_t voff = (size_t)(kv0 + 64);
      char* kb = (char*)&sK[cur ^ 1][0] + (w << 10);
      char* vb = (char*)&sV[cur ^ 1][0] + (w << 10);
      gl_lds16(kstage0 + koff, kb);
      gl_lds16(kstage1 + koff, kb + 4096);
      gl_lds16(vstage0 + voff, vb);
      gl_lds16(vstage1 + voff, vb + 4096);
    }

    qs_tile(A, &sK[cur][0], &sV[cur][0], kv0, kt == nkvA - 1, l15, l4, xsw, s0, s1, hi);
    if (kt < nkvB)
      qs_tile(B, &sK[cur][0], &sV[cur][0], kv0, kt == nkvB - 1, l15, l4, xsw, s0, s1, hi);

    asm volatile("s_waitcnt vmcnt(0)" ::: "memory");
    __syncthreads();
  }

  qs_write(A, Ctx, b, h, qtA, w, l15, l4);
  qs_write(B, Ctx, b, h, qtB, w, l15, l4);
}

// ---------------------------------------------------------------------------
extern "C" void kernel_launch(void* const* d_in, const int* in_sizes, int n_in,
                              void* d_out, int out_size, void* d_ws, size_t ws_size,
                              hipStream_t stream) {
  (void)in_sizes; (void)n_in; (void)out_size; (void)ws_size;
  const float* x  = (const float*)d_in[0];
  const float* Wq = (const float*)d_in[1];
  const float* Wk = (const float*)d_in[2];
  const float* Wv = (const float*)d_in[3];
  const float* Wo = (const float*)d_in[4];
  const float* bo = (const float*)d_in[5];
  float* out = (float*)d_out;

  char* ws = (char*)d_ws;
  unsigned short* x_bf   = (unsigned short*)(ws);                        // 8 MiB (aliased w/ Ctx)
  unsigned short* Ctx    = (unsigned short*)(ws);                        // 8 MiB
  unsigned short* QKVb   = (unsigned short*)(ws + (size_t)( 8u << 20));  // 12 MiB
  unsigned short* Wqkv_t = (unsigned short*)(ws + (size_t)(20u << 20));  // 3 MiB
  unsigned short* Wo_t   = (unsigned short*)(ws + (size_t)(23u << 20));  // 2 MiB
  unsigned short* Vtb    = (unsigned short*)(ws + (size_t)(25u << 20));  // 2 MiB

  const int M = BB * SS;  // 4096

  cast_x_kernel<<<dim3((M * EMB) / (256 * 4)), 256, 0, stream>>>(x, x_bf);
  transpose_cast_kernel<<<dim3(16, 16), 256, 0, stream>>>(Wq, Wqkv_t, 1024);
  transpose_cast_kernel<<<dim3(16, 4),  256, 0, stream>>>(Wk, Wqkv_t + (size_t)1024 * 1024, 256);
  transpose_cast_kernel<<<dim3(16, 4),  256, 0, stream>>>(Wv, Wqkv_t + (size_t)1280 * 1024, 256);
  transpose_cast_kernel<<<dim3(16, 16), 256, 0, stream>>>(Wo, Wo_t, 1024);

  gemm128<true, false><<<dim3(M / 128, QKVD / 128), 256, 0, stream>>>(
      x_bf, Wqkv_t, QKVb, nullptr, QKVD, EMB);

  transpose_v<<<dim3(SS / 64, 8), 256, 0, stream>>>(QKVb, Vtb);

  attn_kernel<<<dim3(512), 256, 0, stream>>>(QKVb, Vtb, Ctx);

  gemm128<false, true><<<dim3(M / 128, EMB / 128), 256, 0, stream>>>(
      Ctx, Wo_t, out, bo, EMB, EMB);
}